// Round 6
// baseline (14.450 us; speedup 1.0000x reference)
//
#include <hip/hip_runtime.h>

#define TOUT_ 481
#define EPS_  1e-8f

typedef __attribute__((ext_vector_type(8))) short bf16x8;
typedef __attribute__((ext_vector_type(4))) float f32x4;

__device__ __forceinline__ unsigned short f2bf(float f) {
  union { float f; unsigned u; } a; a.f = f;
  unsigned r = a.u + 0x7fffu + ((a.u >> 16) & 1u);
  return (unsigned short)(r >> 16);
}
__device__ __forceinline__ float bf2f(unsigned short h) {
  union { unsigned u; float f; } a; a.u = ((unsigned)h) << 16;
  return a.f;
}

// Grid: blockIdx = b*8 + c. Block = 512 thr (8 waves), full t-range per block.
// out[b,t,k2=4c+o] = pp(t,o) + min_s( kk[s,o] + sum_u A[t,u]*B[u,(s,o)] )
// Main loop / fragment / store mappings verified in R4/R5.
__global__ __launch_bounds__(512) void lsd_mfma3(
    const float* __restrict__ x, const float* __restrict__ kern,
    float* __restrict__ out) {
  __shared__ alignas(16) unsigned short Bls[2048];  // [so][j]: nonzero 8 bf16
  __shared__ float kkls[256];            // kk[so]
  __shared__ unsigned short lxb[544];    // bf16 xn channel c (zero-padded)
  __shared__ unsigned int   lxp[528];    // lxp[m] = (lxb[m], lxb[m+1])
  __shared__ float wsum[512];            // sliding sum of squares, window 8
  __shared__ float red[128];
  __shared__ float cstat[16];

  int tid  = threadIdx.x;
  int lane = tid & 63;
  int wv   = tid >> 6;
  int b    = blockIdx.x >> 3;
  int c    = blockIdx.x & 7;

  // ---- kernel loads: 8 threads per s, pair-partitioned (pairs j≡q8 mod 8)
  //      so the owner's B columns are among this thread's own loads ----
  int s = tid >> 3, q8 = tid & 7;
  const float4* kern4 = reinterpret_cast<const float4*>(kern);
  float4 kvA[8];
  #pragma unroll
  for (int m = 0; m < 4; ++m) {
    int j = q8 + 8 * m;                  // pair index within s (0..31)
    kvA[2 * m]     = kern4[s * 64 + 2 * j];
    kvA[2 * m + 1] = kern4[s * 64 + 2 * j + 1];
  }
  const float4* x4 = reinterpret_cast<const float4*>(x) + b * 1024;
  float4 xv0 = x4[tid];
  float4 xv1 = x4[tid + 512];

  // ---- kernel stats (8 threads per s) ----
  float ksum = 0.f, ksq = 0.f;
  #pragma unroll
  for (int u = 0; u < 8; ++u) {
    float4 f = kvA[u];
    ksum += f.x + f.y + f.z + f.w;
    ksq = fmaf(f.x, f.x, ksq); ksq = fmaf(f.y, f.y, ksq);
    ksq = fmaf(f.z, f.z, ksq); ksq = fmaf(f.w, f.w, ksq);
  }
  ksum += __shfl_xor(ksum, 1, 64); ksq += __shfl_xor(ksq, 1, 64);
  ksum += __shfl_xor(ksum, 2, 64); ksq += __shfl_xor(ksq, 2, 64);
  ksum += __shfl_xor(ksum, 4, 64); ksq += __shfl_xor(ksq, 4, 64);
  float kmean = ksum * (1.0f / 256.0f);
  float kvar  = fmaxf(ksq * (1.0f / 256.0f) - kmean * kmean, 0.0f);
  float krstd = 1.0f / (sqrtf(kvar) + EPS_);

  // ---- B build: owner threads (4 per s), columns already in kvA ----
  {
    int o_own = (q8 - 4 * c) & 7;        // owner iff < 4; then pair 4c+o_own
    if (o_own < 4) {
      int m_own = (4 * c + o_own - q8) >> 3;    // which of my 4 pairs
      float4 pa = kvA[2 * m_own], pb = kvA[2 * m_own + 1];
      float vv[8] = {pa.x, pa.y, pa.z, pa.w, pb.x, pb.y, pb.z, pb.w};
      union { unsigned u[4]; bf16x8 v; } bw;
      float kk = 0.f;
      #pragma unroll
      for (int jj = 0; jj < 4; ++jj) {
        float vn0 = (vv[2 * jj]     - kmean) * krstd;
        float vn1 = (vv[2 * jj + 1] - kmean) * krstd;
        unsigned short n0 = f2bf(-2.0f * vn0);
        unsigned short n1 = f2bf(-2.0f * vn1);
        float vq0 = bf2f(f2bf(vn0));
        float vq1 = bf2f(f2bf(vn1));
        kk = fmaf(vq0, vq0, kk);
        kk = fmaf(vq1, vq1, kk);
        bw.u[jj] = (unsigned)n0 | ((unsigned)n1 << 16);
      }
      int so = s * 4 + o_own;
      *reinterpret_cast<bf16x8*>(&Bls[so * 8]) = bw.v;
      kkls[so] = kk;
    }
  }

  // ---- x channel stats ----
  float4 s4v = {0, 0, 0, 0}, q4v = {0, 0, 0, 0};
  {
    s4v.x = xv0.x + xv1.x; s4v.y = xv0.y + xv1.y;
    s4v.z = xv0.z + xv1.z; s4v.w = xv0.w + xv1.w;
    q4v.x = fmaf(xv0.x, xv0.x, xv1.x * xv1.x);
    q4v.y = fmaf(xv0.y, xv0.y, xv1.y * xv1.y);
    q4v.z = fmaf(xv0.z, xv0.z, xv1.z * xv1.z);
    q4v.w = fmaf(xv0.w, xv0.w, xv1.w * xv1.w);
  }
  #pragma unroll
  for (int m = 2; m <= 32; m <<= 1) {
    s4v.x += __shfl_xor(s4v.x, m, 64); s4v.y += __shfl_xor(s4v.y, m, 64);
    s4v.z += __shfl_xor(s4v.z, m, 64); s4v.w += __shfl_xor(s4v.w, m, 64);
    q4v.x += __shfl_xor(q4v.x, m, 64); q4v.y += __shfl_xor(q4v.y, m, 64);
    q4v.z += __shfl_xor(q4v.z, m, 64); q4v.w += __shfl_xor(q4v.w, m, 64);
  }
  if (lane < 2) {
    int base = wv * 16 + lane * 8;
    red[base + 0] = s4v.x; red[base + 1] = s4v.y;
    red[base + 2] = s4v.z; red[base + 3] = s4v.w;
    red[base + 4] = q4v.x; red[base + 5] = q4v.y;
    red[base + 6] = q4v.z; red[base + 7] = q4v.w;
  }
  __syncthreads();                       // sync1: red (Bls/kkls also done)
  if (tid < 8) {
    int g = tid >> 2, cp = tid & 3;
    float sm = 0.f, sq = 0.f;
    #pragma unroll
    for (int w = 0; w < 8; ++w) {
      sm += red[w * 16 + g * 8 + cp];
      sq += red[w * 16 + g * 8 + 4 + cp];
    }
    float mean = sm * (1.0f / 512.0f);
    float var  = fmaxf(sq * (1.0f / 512.0f) - mean * mean, 0.0f);
    cstat[tid]     = mean;
    cstat[8 + tid] = 1.0f / (sqrtf(var) + EPS_);
  }
  __syncthreads();                       // sync2: cstat

  // ---- bf16 normalized channel from registers ----
  if ((tid & 1) == (c >> 2)) {
    float cm = cstat[c], cr = cstat[8 + c];
    int t = tid >> 1;
    float v0 = (c & 2) ? ((c & 1) ? xv0.w : xv0.z) : ((c & 1) ? xv0.y : xv0.x);
    float v1 = (c & 2) ? ((c & 1) ? xv1.w : xv1.z) : ((c & 1) ? xv1.y : xv1.x);
    lxb[t]       = f2bf((v0 - cm) * cr);
    lxb[t + 256] = f2bf((v1 - cm) * cr);
  }
  if (tid < 32) lxb[512 + tid] = 0;
  __syncthreads();                       // sync3: lxb

  // ---- B fragments + prebuilt C-in ----
  int l15 = lane & 15, kch = lane >> 4;
  bool match = (kch == (l15 & 3));
  bf16x8 Bf[16];
  f32x4  cin[16];
  #pragma unroll
  for (int g = 0; g < 16; ++g) {
    int so = g * 16 + l15;
    bf16x8 z = {0, 0, 0, 0, 0, 0, 0, 0};
    Bf[g] = match ? *reinterpret_cast<const bf16x8*>(&Bls[so * 8]) : z;
    float kkv = kkls[so];
    cin[g][0] = kkv; cin[g][1] = kkv; cin[g][2] = kkv; cin[g][3] = kkv;
  }

  // ---- pair table + sliding sum of squares ----
  for (int i = tid; i < 528; i += 512)
    lxp[i] = (unsigned)lxb[i] | ((unsigned)lxb[i + 1] << 16);
  {
    int m = tid;
    float acc = 0.f;
    #pragma unroll
    for (int j = 0; j < 8; ++j) { float v = bf2f(lxb[m + j]); acc = fmaf(v, v, acc); }
    wsum[m] = acc;
  }
  __syncthreads();                       // sync4: lxp/wsum

  // ---- main loop (R4/R5-verified): 31 tiles over 8 waves ----
  int la = l15 + 8 * kch;
  for (int gt = wv; gt < 31; gt += 8) {
    int t0 = gt * 16;
    int p  = t0 + la;
    union { unsigned ui[4]; bf16x8 v; } au;
    au.ui[0] = lxp[p];     au.ui[1] = lxp[p + 2];
    au.ui[2] = lxp[p + 4]; au.ui[3] = lxp[p + 6];

    f32x4 mn = {3.0e38f, 3.0e38f, 3.0e38f, 3.0e38f};
    #pragma unroll
    for (int g = 0; g < 16; ++g) {
      f32x4 d = __builtin_amdgcn_mfma_f32_16x16x32_bf16(au.v, Bf[g], cin[g], 0, 0, 0);
      mn[0] = fminf(mn[0], d[0]); mn[1] = fminf(mn[1], d[1]);
      mn[2] = fminf(mn[2], d[2]); mn[3] = fminf(mn[3], d[3]);
    }
    #pragma unroll
    for (int r = 0; r < 4; ++r) {
      mn[r] = fminf(mn[r], __shfl_xor(mn[r], 4, 64));
      mn[r] = fminf(mn[r], __shfl_xor(mn[r], 8, 64));
    }
    int o = lane & 3;
    float ma = (lane & 4) ? mn[1] : mn[0];
    float mb = (lane & 4) ? mn[3] : mn[2];
    float mv = (lane & 8) ? mb : ma;
    int t = t0 + (lane >> 4) * 4 + ((lane >> 2) & 3);
    if (t < TOUT_)
      out[(b * TOUT_ + t) * 32 + c * 4 + o] = wsum[t + 8 * o] + mv;
  }
}

extern "C" void kernel_launch(void* const* d_in, const int* in_sizes, int n_in,
                              void* d_out, int out_size, void* d_ws, size_t ws_size,
                              hipStream_t stream) {
  const float* x    = (const float*)d_in[0];
  const float* kern = (const float*)d_in[1];
  float* out = (float*)d_out;
  lsd_mfma3<<<128, 512, 0, stream>>>(x, kern, out);
}